// Round 6
// baseline (28005.411 us; speedup 1.0000x reference)
//
#include <hip/hip_runtime.h>
#include <math.h>
#include <float.h>
#include <mutex>

// Problem constants (match reference)
#define N_PTS  32768
#define NS     2048      // N_PTS/16 downsample
#define CD     256
#define KC     5
#define TPB    512       // kmeans kernel
#define TPB_F  1024      // FPS kernel: 32 pts/thread, d in registers, pos streamed from L2
#define MAX_IT 100
#define TOLV   1e-3f
#define DYN_K  131072    // kmeans: pos_s(24576) + stag(65792 @24576..90368) + mdbuf(@98304)

struct Sm {
  int   sel[NS];        // FPS-selected indices into the 32768 points
  int   idx[NS];        // cluster assignment of sampled points
  float cm[KC][CD];     // feature-space centroids
  float cc2h[KC];       // 0.5*|c|^2
  float c3[KC][3];      // position-space centroids
  float cnt[KC];        // cluster counts
  float wc[8][KC];      // per-wave count partials
  float redf[8];
  int   redi[8];
  int   far5[KC];
};

// ---------- block reductions (512 threads = 8 waves) ----------
__device__ __forceinline__ void block_argmax(float v, int i, Sm& sm, float& bv, int& bi) {
  #pragma unroll
  for (int off = 32; off; off >>= 1) {
    float v2 = __shfl_xor(v, off);
    int   i2 = __shfl_xor(i, off);
    if (v2 > v || (v2 == v && i2 < i)) { v = v2; i = i2; }
  }
  __syncthreads();
  if ((threadIdx.x & 63) == 0) { sm.redf[threadIdx.x >> 6] = v; sm.redi[threadIdx.x >> 6] = i; }
  __syncthreads();
  bv = sm.redf[0]; bi = sm.redi[0];
  #pragma unroll
  for (int g = 1; g < 8; g++) {
    float v2 = sm.redf[g]; int i2 = sm.redi[g];
    if (v2 > bv || (v2 == bv && i2 < bi)) { bv = v2; bi = i2; }
  }
}

__device__ __forceinline__ float block_sum(float v, Sm& sm) {
  #pragma unroll
  for (int off = 32; off; off >>= 1) v += __shfl_xor(v, off);
  __syncthreads();
  if ((threadIdx.x & 63) == 0) sm.redf[threadIdx.x >> 6] = v;
  __syncthreads();
  float s = 0.f;
  #pragma unroll
  for (int g = 0; g < 8; g++) s += sm.redf[g];
  return s;  // identical in all threads
}

__device__ __forceinline__ void reduce_counts(Sm& sm, float cn[KC]) {
  const int w = threadIdx.x >> 6, l = threadIdx.x & 63;
  #pragma unroll
  for (int k = 0; k < KC; k++) {
    float s = cn[k];
    #pragma unroll
    for (int off = 32; off; off >>= 1) s += __shfl_xor(s, off);
    cn[k] = s;
  }
  __syncthreads();
  if (l == 0) {
    #pragma unroll
    for (int k = 0; k < KC; k++) sm.wc[w][k] = cn[k];
  }
  __syncthreads();
  if (threadIdx.x == 0) {
    #pragma unroll
    for (int k = 0; k < KC; k++) {
      float s = 0.f;
      #pragma unroll
      for (int g = 0; g < 8; g++) s += sm.wc[g][k];
      sm.cnt[k] = s;
    }
  }
  __syncthreads();
}

__device__ void top5(Sm& sm, float* mdbuf) {
  for (int r5 = 0; r5 < KC; r5++) {
    float lv = -1.f; int li = 0x7fffffff;
    #pragma unroll
    for (int r = 0; r < 4; r++) {
      const int i = 4 * threadIdx.x + r;
      const float v = mdbuf[i];
      if (v > lv) { lv = v; li = i; }
    }
    float bv; int bi;
    block_argmax(lv, li, sm, bv, bi);
    if (threadIdx.x == 0) { sm.far5[r5] = bi; mdbuf[bi] = -2.f; }
    __syncthreads();
  }
}

// ---------- kmeans phases on features ----------
// iteration-0 assignment: fea[:, :3] vs 3-d centroids c3
__device__ void assign3(Sm& sm, const float* feaT) {
  const int tid = threadIdx.x;
  const float4 q0 = *(const float4*)&feaT[0 * NS + 4 * tid];
  const float4 q1 = *(const float4*)&feaT[1 * NS + 4 * tid];
  const float4 q2 = *(const float4*)&feaT[2 * NS + 4 * tid];
  const float x0[4] = {q0.x, q0.y, q0.z, q0.w};
  const float x1[4] = {q1.x, q1.y, q1.z, q1.w};
  const float x2[4] = {q2.x, q2.y, q2.z, q2.w};
  float cn[KC] = {0.f, 0.f, 0.f, 0.f, 0.f};
  #pragma unroll
  for (int r = 0; r < 4; r++) {
    float best = FLT_MAX; int bk = 0;
    #pragma unroll
    for (int k = 0; k < KC; k++) {
      const float d0 = x0[r] - sm.c3[k][0];
      const float d1 = x1[r] - sm.c3[k][1];
      const float d2 = x2[r] - sm.c3[k][2];
      const float s = d0 * d0 + d1 * d1 + d2 * d2;
      if (s < best) { best = s; bk = k; }
    }
    sm.idx[4 * tid + r] = bk;
    #pragma unroll
    for (int k = 0; k < KC; k++) cn[k] += (bk == k) ? 1.f : 0.f;
  }
  reduce_counts(sm, cn);
}

// full 256-dim assignment via dot trick: argmin|x-c|^2 == argmax(x.c - 0.5|c|^2)
__device__ void assign_full(Sm& sm, const float* feaT) {
  const int tid = threadIdx.x;
  float dot[KC][4];
  #pragma unroll
  for (int k = 0; k < KC; k++) { dot[k][0]=0.f; dot[k][1]=0.f; dot[k][2]=0.f; dot[k][3]=0.f; }
  #pragma unroll 4
  for (int j = 0; j < CD; j++) {
    const float4 v = *(const float4*)&feaT[(size_t)j * NS + 4 * tid];
    #pragma unroll
    for (int k = 0; k < KC; k++) {
      const float c = sm.cm[k][j];
      dot[k][0] += v.x * c; dot[k][1] += v.y * c;
      dot[k][2] += v.z * c; dot[k][3] += v.w * c;
    }
  }
  float cn[KC] = {0.f, 0.f, 0.f, 0.f, 0.f};
  #pragma unroll
  for (int r = 0; r < 4; r++) {
    float best = dot[0][r] - sm.cc2h[0]; int bk = 0;
    #pragma unroll
    for (int k = 1; k < KC; k++) {
      const float s = dot[k][r] - sm.cc2h[k];
      if (s > best) { best = s; bk = k; }
    }
    sm.idx[4 * tid + r] = bk;
    #pragma unroll
    for (int k = 0; k < KC; k++) cn[k] += (bk == k) ? 1.f : 0.f;
  }
  reduce_counts(sm, cn);
}

// computeCentroids on features: sums/counts -> cm, sse over dims 0..2, empty fixup, cc2h
__device__ float centroids_fea(Sm& sm, float* wbuf, float* mdbuf,
                               const float* fea_all, const float* feaT) {
  const int tid = threadIdx.x, w = tid >> 6, l = tid & 63;
  // per-wave partial sums (wave w owns points [w*256, w*256+256))
  float4 acc[KC];
  #pragma unroll
  for (int k = 0; k < KC; k++) acc[k] = make_float4(0.f, 0.f, 0.f, 0.f);
  #pragma unroll 8
  for (int ii = 0; ii < 256; ii++) {
    const int i = (w << 8) + ii;
    const int k = __builtin_amdgcn_readfirstlane(sm.idx[i]);
    const float4 v = *(const float4*)&fea_all[(size_t)sm.sel[i] * CD + 4 * l];
    switch (k) {
      case 0: acc[0].x += v.x; acc[0].y += v.y; acc[0].z += v.z; acc[0].w += v.w; break;
      case 1: acc[1].x += v.x; acc[1].y += v.y; acc[1].z += v.z; acc[1].w += v.w; break;
      case 2: acc[2].x += v.x; acc[2].y += v.y; acc[2].z += v.z; acc[2].w += v.w; break;
      case 3: acc[3].x += v.x; acc[3].y += v.y; acc[3].z += v.z; acc[3].w += v.w; break;
      default: acc[4].x += v.x; acc[4].y += v.y; acc[4].z += v.z; acc[4].w += v.w; break;
    }
  }
  #pragma unroll
  for (int k = 0; k < KC; k++) *(float4*)&wbuf[(w * KC + k) * CD + 4 * l] = acc[k];
  __syncthreads();
  // reduce 8 waves + divide
  for (int e = tid; e < KC * CD; e += TPB) {
    float s = 0.f;
    #pragma unroll
    for (int g = 0; g < 8; g++) s += wbuf[g * KC * CD + e];
    (&sm.cm[0][0])[e] = s / fmaxf(sm.cnt[e >> 8], 1.f);
  }
  __syncthreads();
  // sse over dims 0..2 (pre-fixup centroids; only non-empty clusters referenced)
  const float4 q0 = *(const float4*)&feaT[0 * NS + 4 * tid];
  const float4 q1 = *(const float4*)&feaT[1 * NS + 4 * tid];
  const float4 q2 = *(const float4*)&feaT[2 * NS + 4 * tid];
  const float x0[4] = {q0.x, q0.y, q0.z, q0.w};
  const float x1[4] = {q1.x, q1.y, q1.z, q1.w};
  const float x2[4] = {q2.x, q2.y, q2.z, q2.w};
  float psum = 0.f;
  #pragma unroll
  for (int r = 0; r < 4; r++) {
    const int k = sm.idx[4 * tid + r];
    const float d0 = x0[r] - sm.cm[k][0];
    const float d1 = x1[r] - sm.cm[k][1];
    const float d2 = x2[r] - sm.cm[k][2];
    psum += d0 * d0 + d1 * d1 + d2 * d2;
  }
  const float sse = sqrtf(block_sum(psum, sm));
  // empty-cluster fixup
  int nmask = 0;
  #pragma unroll
  for (int k = 0; k < KC; k++) nmask |= (sm.cnt[k] == 0.f) ? (1 << k) : 0;
  if (nmask) {
    float4 dd[KC];
    #pragma unroll
    for (int k = 0; k < KC; k++) dd[k] = make_float4(0.f, 0.f, 0.f, 0.f);
    #pragma unroll 4
    for (int j = 0; j < CD; j++) {
      const float4 v = *(const float4*)&feaT[(size_t)j * NS + 4 * tid];
      #pragma unroll
      for (int k = 0; k < KC; k++) {
        const float c = sm.cm[k][j];
        const float t0 = v.x - c, t1 = v.y - c, t2 = v.z - c, t3 = v.w - c;
        dd[k].x += t0 * t0; dd[k].y += t1 * t1; dd[k].z += t2 * t2; dd[k].w += t3 * t3;
      }
    }
    #pragma unroll
    for (int r = 0; r < 4; r++) {
      float s = 0.f;
      #pragma unroll
      for (int k = 0; k < KC; k++) {
        if (sm.cnt[k] > 0.f) {
          const float d2v = (r == 0) ? dd[k].x : (r == 1) ? dd[k].y : (r == 2) ? dd[k].z : dd[k].w;
          s += sqrtf(fmaxf(d2v, 0.f) + 1e-12f);
        }
      }
      mdbuf[4 * tid + r] = s;
    }
    __syncthreads();
    top5(sm, mdbuf);
    int cum = 0;
    for (int k = 0; k < KC; k++) {   // uniform across threads
      if (sm.cnt[k] == 0.f) {
        const int rk = (cum < KC) ? cum : (KC - 1);
        const int src = sm.far5[rk];
        const size_t row = (size_t)sm.sel[src] * CD;
        for (int d = tid; d < CD; d += TPB) sm.cm[k][d] = fea_all[row + d];
        cum++;
      }
    }
    __syncthreads();
  }
  // cc2h (after fixup, for next assignment)
  if (tid < KC * 64) {
    const float4 c = *(const float4*)&sm.cm[w][4 * l];
    float s = c.x * c.x + c.y * c.y + c.z * c.z + c.w * c.w;
    #pragma unroll
    for (int off = 32; off; off >>= 1) s += __shfl_xor(s, off);
    if (l == 0) sm.cc2h[w] = 0.5f * s;
  }
  __syncthreads();
  return sse;
}

// ---------- FPS kernel: 1024 threads, 32 CONSECUTIVE pts/thread ----------
// Design: d[32] lives in REGISTERS (32 VGPRs, fully static indices); positions are
// STREAMED from L2 every iteration (24 contiguous float4 loads/thread = 384 B).
// The asm memory clobber at the top of the t-loop blocks LICM from hoisting the
// position loads into ~96 registers — which is the allocator spill-trap that cost
// rounds 1/3/4 (allocator refuses >64/128 VGPRs and scratch-spills: 18.4 ms).
// Register footprint: 32 d + ~12 in-flight + ~15 temps ~= 60 -> no spill possible.
// No LDS d-array -> the 2.54e7 LDS bank-conflict cycles vanish.
__global__ __launch_bounds__(TPB_F) void fps_kernel(const float* __restrict__ pfirst,
                                                    const float* __restrict__ psec,
                                                    int* __restrict__ sel_base) {
  const int b = blockIdx.x;                  // 0,1 -> p0first; 2,3 -> p0sec
  const float* pos = ((b < 2) ? pfirst : psec) + (size_t)(b & 1) * N_PTS * 3;
  int* selg = sel_base + (size_t)b * NS * CD;   // slab-start overlay
  __shared__ float rf2[2][16];
  __shared__ int   ri2[2][16];
  const int tid = threadIdx.x, w = tid >> 6, l = tid & 63;

  float dreg[8][4];                          // d[32] in registers, static indices only
  #pragma unroll
  for (int g = 0; g < 8; g++) {
    dreg[g][0] = 1e10f; dreg[g][1] = 1e10f; dreg[g][2] = 1e10f; dreg[g][3] = 1e10f;
  }
  if (tid == 0) selg[0] = 0;
  float lx = pos[0], ly = pos[1], lz = pos[2];

  const int j0 = 32 * tid;                   // consecutive ownership [j0, j0+32)
  for (int t = 1; t < NS; t++) {
    asm volatile("" ::: "memory");           // force per-iteration reload of positions
    float tmax = -1.f; int targ = 0x7fffffff;
    #pragma unroll
    for (int g = 0; g < 8; g++) {
      const int p4 = j0 + 4 * g;             // 4 points, 48 B, 16B-aligned
      const float4 a  = *(const float4*)&pos[3 * p4 + 0];
      const float4 bq = *(const float4*)&pos[3 * p4 + 4];
      const float4 c  = *(const float4*)&pos[3 * p4 + 8];
      {
        const float dx = a.x - lx, dy = a.y - ly, dz = a.z - lz;
        dreg[g][0] = fminf(dreg[g][0], dx * dx + dy * dy + dz * dz);
        if (dreg[g][0] > tmax) { tmax = dreg[g][0]; targ = p4; }
      }
      {
        const float dx = a.w - lx, dy = bq.x - ly, dz = bq.y - lz;
        dreg[g][1] = fminf(dreg[g][1], dx * dx + dy * dy + dz * dz);
        if (dreg[g][1] > tmax) { tmax = dreg[g][1]; targ = p4 + 1; }
      }
      {
        const float dx = bq.z - lx, dy = bq.w - ly, dz = c.x - lz;
        dreg[g][2] = fminf(dreg[g][2], dx * dx + dy * dy + dz * dz);
        if (dreg[g][2] > tmax) { tmax = dreg[g][2]; targ = p4 + 2; }
      }
      {
        const float dx = c.y - lx, dy = c.z - ly, dz = c.w - lz;
        dreg[g][3] = fminf(dreg[g][3], dx * dx + dy * dy + dz * dz);
        if (dreg[g][3] > tmax) { tmax = dreg[g][3]; targ = p4 + 3; }
      }
    }
    // wave-level (value desc, index asc) argmax
    #pragma unroll
    for (int off = 32; off; off >>= 1) {
      const float v2 = __shfl_xor(tmax, off);
      const int   i2 = __shfl_xor(targ, off);
      if (v2 > tmax || (v2 == tmax && i2 < targ)) { tmax = v2; targ = i2; }
    }
    // cross-wave via parity-double-buffered slots: single barrier per iteration
    const int par = t & 1;
    if (l == 0) { rf2[par][w] = tmax; ri2[par][w] = targ; }
    __syncthreads();
    float bv = rf2[par][0]; int bi = ri2[par][0];
    #pragma unroll
    for (int g2 = 1; g2 < 16; g2++) {
      const float v2 = rf2[par][g2]; const int i2 = ri2[par][g2];
      if (v2 > bv || (v2 == bv && i2 < bi)) { bv = v2; bi = i2; }
    }
    if (tid == 0) selg[t] = bi;
    lx = pos[3 * bi]; ly = pos[3 * bi + 1]; lz = pos[3 * bi + 2];  // same-addr broadcast, L1-hit
  }
}

// ---------- per-branch kmeans kernel (512 threads; verified round-0 code) ----------
__global__ __launch_bounds__(TPB) void branch_kernel(const float* __restrict__ logits,
                                                     const float* __restrict__ logits1,
                                                     const float* __restrict__ pfirst,
                                                     const float* __restrict__ psec,
                                                     float* __restrict__ feaT_base,
                                                     float* __restrict__ accum) {
  const int b = blockIdx.x;                  // 0,1 -> logits/p0first; 2,3 -> logits1/p0sec
  const float* fea_all = ((b < 2) ? logits : logits1) + (size_t)(b & 1) * N_PTS * CD;
  const float* pos     = ((b < 2) ? pfirst : psec) + (size_t)(b & 1) * N_PTS * 3;
  float* feaT = feaT_base + (size_t)b * NS * CD;   // [CD][NS] transposed sampled features
  const int* selg = (const int*)feaT;              // overlay: read fully before feaT writes

  __shared__ Sm sm;
  extern __shared__ char dynraw[];
  const int tid = threadIdx.x, w = tid >> 6, l = tid & 63;

  // load FPS selection (must complete before any feaT write - barrier below)
  for (int i = tid; i < NS; i += TPB) sm.sel[i] = selg[i];
  __syncthreads();

  // ================= gather sampled pos into LDS =================
  float* pos_s = (float*)dynraw;             // [NS*3] 0..24576
  float* stag  = (float*)(dynraw + 24576);   // [64][257] = 65792 B -> 24576..90368
  float* wbuf  = (float*)(dynraw + 24576);   // 40960 B, reused after transpose
  float* mdbuf = (float*)(dynraw + 98304);   // [NS] 8192 B -> 98304..106496 (clear of stag)
  for (int i = tid; i < NS; i += TPB) {
    const int s = sm.sel[i];
    pos_s[3 * i] = pos[3 * s]; pos_s[3 * i + 1] = pos[3 * s + 1]; pos_s[3 * i + 2] = pos[3 * s + 2];
  }

  // ================= gather + transpose sampled features -> feaT =================
  for (int tile = 0; tile < NS; tile += 64) {
    __syncthreads();
    for (int rr = w; rr < 64; rr += 8) {
      const int srow = sm.sel[tile + rr];
      const float4 v = *(const float4*)&fea_all[(size_t)srow * CD + 4 * l];
      float* dst = &stag[rr * 257 + 4 * l];
      dst[0] = v.x; dst[1] = v.y; dst[2] = v.z; dst[3] = v.w;
    }
    __syncthreads();
    for (int dd = 0; dd < 32; dd++) {
      const int dim = w * 32 + dd;
      feaT[(size_t)dim * NS + tile + l] = stag[l * 257 + dim];
    }
  }
  __syncthreads();

  // ================= initial centroids (greedy, on positions) =================
  if (tid == 0) { sm.c3[0][0] = pos_s[0]; sm.c3[0][1] = pos_s[1]; sm.c3[0][2] = pos_s[2]; }
  __syncthreads();
  for (int k = 1; k < KC; k++) {
    float lv = -1.f; int li = 0x7fffffff;
    #pragma unroll
    for (int r = 0; r < 4; r++) {
      const int i = 4 * tid + r;
      const float x = pos_s[3 * i], y = pos_s[3 * i + 1], z = pos_s[3 * i + 2];
      float a = 0.f;
      for (int j = 0; j < k; j++) {
        const float dx = x - sm.c3[j][0], dy = y - sm.c3[j][1], dz = z - sm.c3[j][2];
        a += dx * dx + dy * dy + dz * dz;
      }
      if (a > lv) { lv = a; li = i; }
    }
    float bv; int bi;
    block_argmax(lv, li, sm, bv, bi);
    if (tid == 0) { sm.c3[k][0] = pos_s[3 * bi]; sm.c3[k][1] = pos_s[3 * bi + 1]; sm.c3[k][2] = pos_s[3 * bi + 2]; }
    __syncthreads();
  }

  // ================= one kmeans step on positions =================
  {
    float a3[KC][3]; float cn[KC];
    #pragma unroll
    for (int k = 0; k < KC; k++) { a3[k][0] = 0.f; a3[k][1] = 0.f; a3[k][2] = 0.f; cn[k] = 0.f; }
    #pragma unroll
    for (int r = 0; r < 4; r++) {
      const int i = 4 * tid + r;
      const float x = pos_s[3 * i], y = pos_s[3 * i + 1], z = pos_s[3 * i + 2];
      float best = FLT_MAX; int bk = 0;
      #pragma unroll
      for (int k = 0; k < KC; k++) {
        const float dx = x - sm.c3[k][0], dy = y - sm.c3[k][1], dz = z - sm.c3[k][2];
        const float s = dx * dx + dy * dy + dz * dz;
        if (s < best) { best = s; bk = k; }
      }
      sm.idx[i] = bk;
      #pragma unroll
      for (int k = 0; k < KC; k++) {
        const float m = (bk == k) ? 1.f : 0.f;
        a3[k][0] += m * x; a3[k][1] += m * y; a3[k][2] += m * z; cn[k] += m;
      }
    }
    reduce_counts(sm, cn);
    #pragma unroll
    for (int k = 0; k < KC; k++) {
      #pragma unroll
      for (int c = 0; c < 3; c++) {
        float s = a3[k][c];
        #pragma unroll
        for (int off = 32; off; off >>= 1) s += __shfl_xor(s, off);
        a3[k][c] = s;
      }
    }
    __syncthreads();
    if (l == 0) {
      #pragma unroll
      for (int k = 0; k < KC; k++) {
        wbuf[w * 16 + k * 3 + 0] = a3[k][0];
        wbuf[w * 16 + k * 3 + 1] = a3[k][1];
        wbuf[w * 16 + k * 3 + 2] = a3[k][2];
      }
    }
    __syncthreads();
    if (tid == 0) {
      for (int k = 0; k < KC; k++)
        for (int c = 0; c < 3; c++) {
          float s = 0.f;
          for (int g = 0; g < 8; g++) s += wbuf[g * 16 + k * 3 + c];
          sm.c3[k][c] = s / fmaxf(sm.cnt[k], 1.f);
        }
    }
    __syncthreads();
  }
  float psum = 0.f;
  #pragma unroll
  for (int r = 0; r < 4; r++) {
    const int i = 4 * tid + r; const int k = sm.idx[i];
    const float dx = pos_s[3 * i] - sm.c3[k][0];
    const float dy = pos_s[3 * i + 1] - sm.c3[k][1];
    const float dz = pos_s[3 * i + 2] - sm.c3[k][2];
    psum += dx * dx + dy * dy + dz * dz;
  }
  const float sse_n = sqrtf(block_sum(psum, sm));
  {  // empty-cluster fixup (positions)
    int nmask = 0;
    #pragma unroll
    for (int k = 0; k < KC; k++) nmask |= (sm.cnt[k] == 0.f) ? (1 << k) : 0;
    if (nmask) {
      #pragma unroll
      for (int r = 0; r < 4; r++) {
        const int i = 4 * tid + r;
        const float x = pos_s[3 * i], y = pos_s[3 * i + 1], z = pos_s[3 * i + 2];
        float s = 0.f;
        for (int k = 0; k < KC; k++) {
          if (sm.cnt[k] > 0.f) {
            const float dx = x - sm.c3[k][0], dy = y - sm.c3[k][1], dz = z - sm.c3[k][2];
            s += sqrtf(dx * dx + dy * dy + dz * dz + 1e-12f);
          }
        }
        mdbuf[i] = s;
      }
      __syncthreads();
      top5(sm, mdbuf);
      if (tid == 0) {
        int cum = 0;
        for (int k = 0; k < KC; k++) {
          if (sm.cnt[k] == 0.f) {
            const int rk = (cum < KC) ? cum : (KC - 1);
            const int src = sm.far5[rk];
            sm.c3[k][0] = pos_s[3 * src]; sm.c3[k][1] = pos_s[3 * src + 1]; sm.c3[k][2] = pos_s[3 * src + 2];
            cum++;
          }
        }
      }
      __syncthreads();
    }
  }

  // ================= kmeans on features =================
  assign3(sm, feaT);
  float sse_fin = centroids_fea(sm, wbuf, mdbuf, fea_all, feaT);
  float sse_pre = sse_fin;
  bool done = fabsf(sse_fin) < TOLV;
  for (int it = 1; it < MAX_IT && !done; it++) {
    assign_full(sm, feaT);
    const float s2 = centroids_fea(sm, wbuf, mdbuf, fea_all, feaT);
    sse_fin = s2;
    done = fabsf(s2 - sse_pre) < TOLV;
    sse_pre = s2;
  }
  if (tid == 0) atomicAdd(&accum[1], sse_n + sse_fin);
}

// ---------- global point loss (cosine similarity) ----------
__global__ __launch_bounds__(256) void gp_kernel(const float* __restrict__ A,
                                                 const float* __restrict__ B,
                                                 float* __restrict__ accum) {
  __shared__ float bacc;
  const int tid = threadIdx.x, l = tid & 63, w = tid >> 6;
  if (tid == 0) bacc = 0.f;
  __syncthreads();
  const int gw = blockIdx.x * 4 + w;
  const int NW = gridDim.x * 4;
  float lsum = 0.f;
  for (int p = gw; p < 65536; p += NW) {
    const float4 a = *(const float4*)&A[(size_t)p * CD + 4 * l];
    const float4 b = *(const float4*)&B[(size_t)p * CD + 4 * l];
    float ab = a.x * b.x + a.y * b.y + a.z * b.z + a.w * b.w;
    float aa = a.x * a.x + a.y * a.y + a.z * a.z + a.w * a.w;
    float bb = b.x * b.x + b.y * b.y + b.z * b.z + b.w * b.w;
    #pragma unroll
    for (int off = 32; off; off >>= 1) {
      ab += __shfl_xor(ab, off); aa += __shfl_xor(aa, off); bb += __shfl_xor(bb, off);
    }
    if (l == 0) lsum += ab / fmaxf(sqrtf(aa) * sqrtf(bb), 1e-8f);
  }
  if (l == 0) atomicAdd(&bacc, lsum);
  __syncthreads();
  if (tid == 0) atomicAdd(&accum[0], bacc);
}

__global__ void fin_kernel(const float* __restrict__ accum, float* __restrict__ out) {
  out[0] = -accum[0] / 65536.0f + accum[1];
}

extern "C" void kernel_launch(void* const* d_in, const int* in_sizes, int n_in,
                              void* d_out, int out_size, void* d_ws, size_t ws_size,
                              hipStream_t stream) {
  const float* logits  = (const float*)d_in[0];
  const float* logits1 = (const float*)d_in[1];
  const float* pfirst  = (const float*)d_in[2];
  const float* psec    = (const float*)d_in[3];
  float* out = (float*)d_out;
  float* wsf = (float*)d_ws;
  float* accum = wsf;            // [0]=sum of cos, [1]=sum of sse
  float* feaT = wsf + 16;        // 4 branches x [CD][NS] = 8 MB; sel overlaid at slab starts

  static std::once_flag once;
  std::call_once(once, []() {
    (void)hipFuncSetAttribute((const void*)branch_kernel,
                              hipFuncAttributeMaxDynamicSharedMemorySize, DYN_K);
    (void)hipGetLastError();
  });

  (void)hipMemsetAsync(accum, 0, 64, stream);
  gp_kernel<<<1024, 256, 0, stream>>>(logits, logits1, accum);
  fps_kernel<<<4, TPB_F, 0, stream>>>(pfirst, psec, (int*)feaT);
  branch_kernel<<<4, TPB, DYN_K, stream>>>(logits, logits1, pfirst, psec, feaT, accum);
  fin_kernel<<<1, 1, 0, stream>>>(accum, out);
}

// Round 7
// 8534.617 us; speedup vs baseline: 3.2814x; 3.2814x over previous
//
#include <hip/hip_runtime.h>
#include <math.h>
#include <float.h>
#include <mutex>

// Problem constants (match reference)
#define N_PTS  32768
#define NS     2048      // N_PTS/16 downsample
#define CD     256
#define KC     5
#define TPB    512       // kmeans kernel
#define TPB_F  512       // FPS kernel threads/block
#define NB_F   8         // FPS blocks per branch: 4096 pts/block, 8 pts/thread (registers)
#define MAX_IT 100
#define TOLV   1e-3f
#define DYN_K  131072    // kmeans: pos_s(24576) + stag(65792 @24576..90368) + mdbuf(@98304)

struct Sm {
  int   sel[NS];        // FPS-selected indices into the 32768 points
  int   idx[NS];        // cluster assignment of sampled points
  float cm[KC][CD];     // feature-space centroids
  float cc2h[KC];       // 0.5*|c|^2
  float c3[KC][3];      // position-space centroids
  float cnt[KC];        // cluster counts
  float wc[8][KC];      // per-wave count partials
  float redf[8];
  int   redi[8];
  int   far5[KC];
};

// ---------- block reductions (512 threads = 8 waves) ----------
__device__ __forceinline__ void block_argmax(float v, int i, Sm& sm, float& bv, int& bi) {
  #pragma unroll
  for (int off = 32; off; off >>= 1) {
    float v2 = __shfl_xor(v, off);
    int   i2 = __shfl_xor(i, off);
    if (v2 > v || (v2 == v && i2 < i)) { v = v2; i = i2; }
  }
  __syncthreads();
  if ((threadIdx.x & 63) == 0) { sm.redf[threadIdx.x >> 6] = v; sm.redi[threadIdx.x >> 6] = i; }
  __syncthreads();
  bv = sm.redf[0]; bi = sm.redi[0];
  #pragma unroll
  for (int g = 1; g < 8; g++) {
    float v2 = sm.redf[g]; int i2 = sm.redi[g];
    if (v2 > bv || (v2 == bv && i2 < bi)) { bv = v2; bi = i2; }
  }
}

__device__ __forceinline__ float block_sum(float v, Sm& sm) {
  #pragma unroll
  for (int off = 32; off; off >>= 1) v += __shfl_xor(v, off);
  __syncthreads();
  if ((threadIdx.x & 63) == 0) sm.redf[threadIdx.x >> 6] = v;
  __syncthreads();
  float s = 0.f;
  #pragma unroll
  for (int g = 0; g < 8; g++) s += sm.redf[g];
  return s;  // identical in all threads
}

__device__ __forceinline__ void reduce_counts(Sm& sm, float cn[KC]) {
  const int w = threadIdx.x >> 6, l = threadIdx.x & 63;
  #pragma unroll
  for (int k = 0; k < KC; k++) {
    float s = cn[k];
    #pragma unroll
    for (int off = 32; off; off >>= 1) s += __shfl_xor(s, off);
    cn[k] = s;
  }
  __syncthreads();
  if (l == 0) {
    #pragma unroll
    for (int k = 0; k < KC; k++) sm.wc[w][k] = cn[k];
  }
  __syncthreads();
  if (threadIdx.x == 0) {
    #pragma unroll
    for (int k = 0; k < KC; k++) {
      float s = 0.f;
      #pragma unroll
      for (int g = 0; g < 8; g++) s += sm.wc[g][k];
      sm.cnt[k] = s;
    }
  }
  __syncthreads();
}

__device__ void top5(Sm& sm, float* mdbuf) {
  for (int r5 = 0; r5 < KC; r5++) {
    float lv = -1.f; int li = 0x7fffffff;
    #pragma unroll
    for (int r = 0; r < 4; r++) {
      const int i = 4 * threadIdx.x + r;
      const float v = mdbuf[i];
      if (v > lv) { lv = v; li = i; }
    }
    float bv; int bi;
    block_argmax(lv, li, sm, bv, bi);
    if (threadIdx.x == 0) { sm.far5[r5] = bi; mdbuf[bi] = -2.f; }
    __syncthreads();
  }
}

// ---------- kmeans phases on features ----------
// iteration-0 assignment: fea[:, :3] vs 3-d centroids c3
__device__ void assign3(Sm& sm, const float* feaT) {
  const int tid = threadIdx.x;
  const float4 q0 = *(const float4*)&feaT[0 * NS + 4 * tid];
  const float4 q1 = *(const float4*)&feaT[1 * NS + 4 * tid];
  const float4 q2 = *(const float4*)&feaT[2 * NS + 4 * tid];
  const float x0[4] = {q0.x, q0.y, q0.z, q0.w};
  const float x1[4] = {q1.x, q1.y, q1.z, q1.w};
  const float x2[4] = {q2.x, q2.y, q2.z, q2.w};
  float cn[KC] = {0.f, 0.f, 0.f, 0.f, 0.f};
  #pragma unroll
  for (int r = 0; r < 4; r++) {
    float best = FLT_MAX; int bk = 0;
    #pragma unroll
    for (int k = 0; k < KC; k++) {
      const float d0 = x0[r] - sm.c3[k][0];
      const float d1 = x1[r] - sm.c3[k][1];
      const float d2 = x2[r] - sm.c3[k][2];
      const float s = d0 * d0 + d1 * d1 + d2 * d2;
      if (s < best) { best = s; bk = k; }
    }
    sm.idx[4 * tid + r] = bk;
    #pragma unroll
    for (int k = 0; k < KC; k++) cn[k] += (bk == k) ? 1.f : 0.f;
  }
  reduce_counts(sm, cn);
}

// full 256-dim assignment via dot trick: argmin|x-c|^2 == argmax(x.c - 0.5|c|^2)
__device__ void assign_full(Sm& sm, const float* feaT) {
  const int tid = threadIdx.x;
  float dot[KC][4];
  #pragma unroll
  for (int k = 0; k < KC; k++) { dot[k][0]=0.f; dot[k][1]=0.f; dot[k][2]=0.f; dot[k][3]=0.f; }
  #pragma unroll 4
  for (int j = 0; j < CD; j++) {
    const float4 v = *(const float4*)&feaT[(size_t)j * NS + 4 * tid];
    #pragma unroll
    for (int k = 0; k < KC; k++) {
      const float c = sm.cm[k][j];
      dot[k][0] += v.x * c; dot[k][1] += v.y * c;
      dot[k][2] += v.z * c; dot[k][3] += v.w * c;
    }
  }
  float cn[KC] = {0.f, 0.f, 0.f, 0.f, 0.f};
  #pragma unroll
  for (int r = 0; r < 4; r++) {
    float best = dot[0][r] - sm.cc2h[0]; int bk = 0;
    #pragma unroll
    for (int k = 1; k < KC; k++) {
      const float s = dot[k][r] - sm.cc2h[k];
      if (s > best) { best = s; bk = k; }
    }
    sm.idx[4 * tid + r] = bk;
    #pragma unroll
    for (int k = 0; k < KC; k++) cn[k] += (bk == k) ? 1.f : 0.f;
  }
  reduce_counts(sm, cn);
}

// computeCentroids on features: sums/counts -> cm, sse over dims 0..2, empty fixup, cc2h
__device__ float centroids_fea(Sm& sm, float* wbuf, float* mdbuf,
                               const float* fea_all, const float* feaT) {
  const int tid = threadIdx.x, w = tid >> 6, l = tid & 63;
  // per-wave partial sums (wave w owns points [w*256, w*256+256))
  float4 acc[KC];
  #pragma unroll
  for (int k = 0; k < KC; k++) acc[k] = make_float4(0.f, 0.f, 0.f, 0.f);
  #pragma unroll 8
  for (int ii = 0; ii < 256; ii++) {
    const int i = (w << 8) + ii;
    const int k = __builtin_amdgcn_readfirstlane(sm.idx[i]);
    const float4 v = *(const float4*)&fea_all[(size_t)sm.sel[i] * CD + 4 * l];
    switch (k) {
      case 0: acc[0].x += v.x; acc[0].y += v.y; acc[0].z += v.z; acc[0].w += v.w; break;
      case 1: acc[1].x += v.x; acc[1].y += v.y; acc[1].z += v.z; acc[1].w += v.w; break;
      case 2: acc[2].x += v.x; acc[2].y += v.y; acc[2].z += v.z; acc[2].w += v.w; break;
      case 3: acc[3].x += v.x; acc[3].y += v.y; acc[3].z += v.z; acc[3].w += v.w; break;
      default: acc[4].x += v.x; acc[4].y += v.y; acc[4].z += v.z; acc[4].w += v.w; break;
    }
  }
  #pragma unroll
  for (int k = 0; k < KC; k++) *(float4*)&wbuf[(w * KC + k) * CD + 4 * l] = acc[k];
  __syncthreads();
  // reduce 8 waves + divide
  for (int e = tid; e < KC * CD; e += TPB) {
    float s = 0.f;
    #pragma unroll
    for (int g = 0; g < 8; g++) s += wbuf[g * KC * CD + e];
    (&sm.cm[0][0])[e] = s / fmaxf(sm.cnt[e >> 8], 1.f);
  }
  __syncthreads();
  // sse over dims 0..2 (pre-fixup centroids; only non-empty clusters referenced)
  const float4 q0 = *(const float4*)&feaT[0 * NS + 4 * tid];
  const float4 q1 = *(const float4*)&feaT[1 * NS + 4 * tid];
  const float4 q2 = *(const float4*)&feaT[2 * NS + 4 * tid];
  const float x0[4] = {q0.x, q0.y, q0.z, q0.w};
  const float x1[4] = {q1.x, q1.y, q1.z, q1.w};
  const float x2[4] = {q2.x, q2.y, q2.z, q2.w};
  float psum = 0.f;
  #pragma unroll
  for (int r = 0; r < 4; r++) {
    const int k = sm.idx[4 * tid + r];
    const float d0 = x0[r] - sm.cm[k][0];
    const float d1 = x1[r] - sm.cm[k][1];
    const float d2 = x2[r] - sm.cm[k][2];
    psum += d0 * d0 + d1 * d1 + d2 * d2;
  }
  const float sse = sqrtf(block_sum(psum, sm));
  // empty-cluster fixup
  int nmask = 0;
  #pragma unroll
  for (int k = 0; k < KC; k++) nmask |= (sm.cnt[k] == 0.f) ? (1 << k) : 0;
  if (nmask) {
    float4 dd[KC];
    #pragma unroll
    for (int k = 0; k < KC; k++) dd[k] = make_float4(0.f, 0.f, 0.f, 0.f);
    #pragma unroll 4
    for (int j = 0; j < CD; j++) {
      const float4 v = *(const float4*)&feaT[(size_t)j * NS + 4 * tid];
      #pragma unroll
      for (int k = 0; k < KC; k++) {
        const float c = sm.cm[k][j];
        const float t0 = v.x - c, t1 = v.y - c, t2 = v.z - c, t3 = v.w - c;
        dd[k].x += t0 * t0; dd[k].y += t1 * t1; dd[k].z += t2 * t2; dd[k].w += t3 * t3;
      }
    }
    #pragma unroll
    for (int r = 0; r < 4; r++) {
      float s = 0.f;
      #pragma unroll
      for (int k = 0; k < KC; k++) {
        if (sm.cnt[k] > 0.f) {
          const float d2v = (r == 0) ? dd[k].x : (r == 1) ? dd[k].y : (r == 2) ? dd[k].z : dd[k].w;
          s += sqrtf(fmaxf(d2v, 0.f) + 1e-12f);
        }
      }
      mdbuf[4 * tid + r] = s;
    }
    __syncthreads();
    top5(sm, mdbuf);
    int cum = 0;
    for (int k = 0; k < KC; k++) {   // uniform across threads
      if (sm.cnt[k] == 0.f) {
        const int rk = (cum < KC) ? cum : (KC - 1);
        const int src = sm.far5[rk];
        const size_t row = (size_t)sm.sel[src] * CD;
        for (int d = tid; d < CD; d += TPB) sm.cm[k][d] = fea_all[row + d];
        cum++;
      }
    }
    __syncthreads();
  }
  // cc2h (after fixup, for next assignment)
  if (tid < KC * 64) {
    const float4 c = *(const float4*)&sm.cm[w][4 * l];
    float s = c.x * c.x + c.y * c.y + c.z * c.z + c.w * c.w;
    #pragma unroll
    for (int off = 32; off; off >>= 1) s += __shfl_xor(s, off);
    if (l == 0) sm.cc2h[w] = 0.5f * s;
  }
  __syncthreads();
  return sse;
}

// ---------- FPS kernel: 8 blocks/branch x 512 threads, 8 pts/thread in REGISTERS ----------
// Round-6 lesson: one CU streaming 384 KB of positions per iteration from L2 is
// floor-bound at ~5-12 us/iter. Fix: 4096 pts/block -> 24 pos floats + 8 d floats
// per thread ~= 32 regs (round 6 proved this footprint stays register-resident,
// VGPR 52, no scratch). Inner loop is pure register VALU. Cross-block argmax per
// iteration via fresh per-t workspace slots: packed u64 = bit63 | fbits<<32 |
// (0xFFFFFFFF-idx) -> u64 max == (max value, min index), matching jnp.argmax
// first-occurrence tie-break. Release store + acquire poll, agent scope (G16).
// 32 blocks << 256 CUs -> co-residency guaranteed; slots zeroed each launch.
__global__ __launch_bounds__(TPB_F) void fps_kernel(const float* __restrict__ pfirst,
                                                    const float* __restrict__ psec,
                                                    int* __restrict__ sel_base,
                                                    unsigned long long* __restrict__ cand) {
  const int br = blockIdx.x >> 3, sub = blockIdx.x & 7;
  const float* pos = ((br < 2) ? pfirst : psec) + (size_t)(br & 1) * N_PTS * 3;
  int* selg = sel_base + (size_t)br * NS * CD;          // slab-start overlay
  unsigned long long* mycand = cand + (size_t)br * NS * NB_F;
  __shared__ float redf[8];
  __shared__ int   redi[8];
  __shared__ int   winLDS;
  const int tid = threadIdx.x, w = tid >> 6, l = tid & 63;
  const int base = sub * 4096;

  float px[8], py[8], pz[8], dd[8];          // 32 registers, static indices only
  #pragma unroll
  for (int k = 0; k < 8; k++) {
    const int p = base + tid + k * TPB_F;
    px[k] = pos[3 * p]; py[k] = pos[3 * p + 1]; pz[k] = pos[3 * p + 2];
    dd[k] = 1e10f;
  }
  if (sub == 0 && tid == 0) selg[0] = 0;
  float lx = pos[0], ly = pos[1], lz = pos[2];

  for (int t = 1; t < NS; t++) {
    // register-only update + local argmax (strict > keeps lowest index; k ascending)
    float bv = -1.f; int bi = 0x7fffffff;
    #pragma unroll
    for (int k = 0; k < 8; k++) {
      const float dx = px[k] - lx, dy = py[k] - ly, dz = pz[k] - lz;
      const float dist = dx * dx + dy * dy + dz * dz;
      dd[k] = fminf(dd[k], dist);
      if (dd[k] > bv) { bv = dd[k]; bi = base + tid + k * TPB_F; }
    }
    // wave-level (value desc, index asc)
    #pragma unroll
    for (int off = 32; off; off >>= 1) {
      const float v2 = __shfl_xor(bv, off);
      const int   i2 = __shfl_xor(bi, off);
      if (v2 > bv || (v2 == bv && i2 < bi)) { bv = v2; bi = i2; }
    }
    if (l == 0) { redf[w] = bv; redi[w] = bi; }
    __syncthreads();
    // block winner -> packed u64 -> workspace slot (release, agent scope)
    if (tid == 0) {
      float cv = redf[0]; int ci = redi[0];
      #pragma unroll
      for (int g = 1; g < 8; g++) {
        if (redf[g] > cv || (redf[g] == cv && redi[g] < ci)) { cv = redf[g]; ci = redi[g]; }
      }
      const unsigned long long pk = (1ULL << 63)
          | ((unsigned long long)__float_as_uint(cv) << 32)
          | (unsigned long long)(0xFFFFFFFFu - (unsigned)ci);
      __hip_atomic_store(&mycand[(size_t)t * NB_F + sub], pk,
                         __ATOMIC_RELEASE, __HIP_MEMORY_SCOPE_AGENT);
    }
    // wave 0 lanes 0..7: poll all 8 slots, reduce, broadcast
    if (w == 0 && l < NB_F) {
      unsigned long long pk = __hip_atomic_load(&mycand[(size_t)t * NB_F + l],
                                                __ATOMIC_ACQUIRE, __HIP_MEMORY_SCOPE_AGENT);
      while (pk == 0ULL) {
        __builtin_amdgcn_s_sleep(1);
        pk = __hip_atomic_load(&mycand[(size_t)t * NB_F + l],
                               __ATOMIC_ACQUIRE, __HIP_MEMORY_SCOPE_AGENT);
      }
      #pragma unroll
      for (int off = 4; off; off >>= 1) {
        const unsigned long long o = __shfl_xor(pk, off, NB_F);
        pk = (o > pk) ? o : pk;
      }
      if (l == 0) {
        const int gi = (int)(0xFFFFFFFFu - (unsigned)(pk & 0xFFFFFFFFull));
        winLDS = gi;
        if (sub == 0) selg[t] = gi;
      }
    }
    __syncthreads();
    const int gbi = winLDS;
    lx = pos[3 * gbi]; ly = pos[3 * gbi + 1]; lz = pos[3 * gbi + 2];  // bcast, L2-hit
  }
}

// ---------- per-branch kmeans kernel (512 threads; round-3/4-verified code) ----------
__global__ __launch_bounds__(TPB) void branch_kernel(const float* __restrict__ logits,
                                                     const float* __restrict__ logits1,
                                                     const float* __restrict__ pfirst,
                                                     const float* __restrict__ psec,
                                                     float* __restrict__ feaT_base,
                                                     float* __restrict__ accum) {
  const int b = blockIdx.x;                  // 0,1 -> logits/p0first; 2,3 -> logits1/p0sec
  const float* fea_all = ((b < 2) ? logits : logits1) + (size_t)(b & 1) * N_PTS * CD;
  const float* pos     = ((b < 2) ? pfirst : psec) + (size_t)(b & 1) * N_PTS * 3;
  float* feaT = feaT_base + (size_t)b * NS * CD;   // [CD][NS] transposed sampled features
  const int* selg = (const int*)feaT;              // overlay: read fully before feaT writes

  __shared__ Sm sm;
  extern __shared__ char dynraw[];
  const int tid = threadIdx.x, w = tid >> 6, l = tid & 63;

  // load FPS selection (must complete before any feaT write - barrier below)
  for (int i = tid; i < NS; i += TPB) sm.sel[i] = selg[i];
  __syncthreads();

  // ================= gather sampled pos into LDS =================
  float* pos_s = (float*)dynraw;             // [NS*3] 0..24576
  float* stag  = (float*)(dynraw + 24576);   // [64][257] = 65792 B -> 24576..90368
  float* wbuf  = (float*)(dynraw + 24576);   // 40960 B, reused after transpose
  float* mdbuf = (float*)(dynraw + 98304);   // [NS] 8192 B -> 98304..106496 (clear of stag)
  for (int i = tid; i < NS; i += TPB) {
    const int s = sm.sel[i];
    pos_s[3 * i] = pos[3 * s]; pos_s[3 * i + 1] = pos[3 * s + 1]; pos_s[3 * i + 2] = pos[3 * s + 2];
  }

  // ================= gather + transpose sampled features -> feaT =================
  for (int tile = 0; tile < NS; tile += 64) {
    __syncthreads();
    for (int rr = w; rr < 64; rr += 8) {
      const int srow = sm.sel[tile + rr];
      const float4 v = *(const float4*)&fea_all[(size_t)srow * CD + 4 * l];
      float* dst = &stag[rr * 257 + 4 * l];
      dst[0] = v.x; dst[1] = v.y; dst[2] = v.z; dst[3] = v.w;
    }
    __syncthreads();
    for (int dd = 0; dd < 32; dd++) {
      const int dim = w * 32 + dd;
      feaT[(size_t)dim * NS + tile + l] = stag[l * 257 + dim];
    }
  }
  __syncthreads();

  // ================= initial centroids (greedy, on positions) =================
  if (tid == 0) { sm.c3[0][0] = pos_s[0]; sm.c3[0][1] = pos_s[1]; sm.c3[0][2] = pos_s[2]; }
  __syncthreads();
  for (int k = 1; k < KC; k++) {
    float lv = -1.f; int li = 0x7fffffff;
    #pragma unroll
    for (int r = 0; r < 4; r++) {
      const int i = 4 * tid + r;
      const float x = pos_s[3 * i], y = pos_s[3 * i + 1], z = pos_s[3 * i + 2];
      float a = 0.f;
      for (int j = 0; j < k; j++) {
        const float dx = x - sm.c3[j][0], dy = y - sm.c3[j][1], dz = z - sm.c3[j][2];
        a += dx * dx + dy * dy + dz * dz;
      }
      if (a > lv) { lv = a; li = i; }
    }
    float bv; int bi;
    block_argmax(lv, li, sm, bv, bi);
    if (tid == 0) { sm.c3[k][0] = pos_s[3 * bi]; sm.c3[k][1] = pos_s[3 * bi + 1]; sm.c3[k][2] = pos_s[3 * bi + 2]; }
    __syncthreads();
  }

  // ================= one kmeans step on positions =================
  {
    float a3[KC][3]; float cn[KC];
    #pragma unroll
    for (int k = 0; k < KC; k++) { a3[k][0] = 0.f; a3[k][1] = 0.f; a3[k][2] = 0.f; cn[k] = 0.f; }
    #pragma unroll
    for (int r = 0; r < 4; r++) {
      const int i = 4 * tid + r;
      const float x = pos_s[3 * i], y = pos_s[3 * i + 1], z = pos_s[3 * i + 2];
      float best = FLT_MAX; int bk = 0;
      #pragma unroll
      for (int k = 0; k < KC; k++) {
        const float dx = x - sm.c3[k][0], dy = y - sm.c3[k][1], dz = z - sm.c3[k][2];
        const float s = dx * dx + dy * dy + dz * dz;
        if (s < best) { best = s; bk = k; }
      }
      sm.idx[i] = bk;
      #pragma unroll
      for (int k = 0; k < KC; k++) {
        const float m = (bk == k) ? 1.f : 0.f;
        a3[k][0] += m * x; a3[k][1] += m * y; a3[k][2] += m * z; cn[k] += m;
      }
    }
    reduce_counts(sm, cn);
    #pragma unroll
    for (int k = 0; k < KC; k++) {
      #pragma unroll
      for (int c = 0; c < 3; c++) {
        float s = a3[k][c];
        #pragma unroll
        for (int off = 32; off; off >>= 1) s += __shfl_xor(s, off);
        a3[k][c] = s;
      }
    }
    __syncthreads();
    if (l == 0) {
      #pragma unroll
      for (int k = 0; k < KC; k++) {
        wbuf[w * 16 + k * 3 + 0] = a3[k][0];
        wbuf[w * 16 + k * 3 + 1] = a3[k][1];
        wbuf[w * 16 + k * 3 + 2] = a3[k][2];
      }
    }
    __syncthreads();
    if (tid == 0) {
      for (int k = 0; k < KC; k++)
        for (int c = 0; c < 3; c++) {
          float s = 0.f;
          for (int g = 0; g < 8; g++) s += wbuf[g * 16 + k * 3 + c];
          sm.c3[k][c] = s / fmaxf(sm.cnt[k], 1.f);
        }
    }
    __syncthreads();
  }
  float psum = 0.f;
  #pragma unroll
  for (int r = 0; r < 4; r++) {
    const int i = 4 * tid + r; const int k = sm.idx[i];
    const float dx = pos_s[3 * i] - sm.c3[k][0];
    const float dy = pos_s[3 * i + 1] - sm.c3[k][1];
    const float dz = pos_s[3 * i + 2] - sm.c3[k][2];
    psum += dx * dx + dy * dy + dz * dz;
  }
  const float sse_n = sqrtf(block_sum(psum, sm));
  {  // empty-cluster fixup (positions)
    int nmask = 0;
    #pragma unroll
    for (int k = 0; k < KC; k++) nmask |= (sm.cnt[k] == 0.f) ? (1 << k) : 0;
    if (nmask) {
      #pragma unroll
      for (int r = 0; r < 4; r++) {
        const int i = 4 * tid + r;
        const float x = pos_s[3 * i], y = pos_s[3 * i + 1], z = pos_s[3 * i + 2];
        float s = 0.f;
        for (int k = 0; k < KC; k++) {
          if (sm.cnt[k] > 0.f) {
            const float dx = x - sm.c3[k][0], dy = y - sm.c3[k][1], dz = z - sm.c3[k][2];
            s += sqrtf(dx * dx + dy * dy + dz * dz + 1e-12f);
          }
        }
        mdbuf[i] = s;
      }
      __syncthreads();
      top5(sm, mdbuf);
      if (tid == 0) {
        int cum = 0;
        for (int k = 0; k < KC; k++) {
          if (sm.cnt[k] == 0.f) {
            const int rk = (cum < KC) ? cum : (KC - 1);
            const int src = sm.far5[rk];
            sm.c3[k][0] = pos_s[3 * src]; sm.c3[k][1] = pos_s[3 * src + 1]; sm.c3[k][2] = pos_s[3 * src + 2];
            cum++;
          }
        }
      }
      __syncthreads();
    }
  }

  // ================= kmeans on features =================
  assign3(sm, feaT);
  float sse_fin = centroids_fea(sm, wbuf, mdbuf, fea_all, feaT);
  float sse_pre = sse_fin;
  bool done = fabsf(sse_fin) < TOLV;
  for (int it = 1; it < MAX_IT && !done; it++) {
    assign_full(sm, feaT);
    const float s2 = centroids_fea(sm, wbuf, mdbuf, fea_all, feaT);
    sse_fin = s2;
    done = fabsf(s2 - sse_pre) < TOLV;
    sse_pre = s2;
  }
  if (tid == 0) atomicAdd(&accum[1], sse_n + sse_fin);
}

// ---------- global point loss (cosine similarity) ----------
__global__ __launch_bounds__(256) void gp_kernel(const float* __restrict__ A,
                                                 const float* __restrict__ B,
                                                 float* __restrict__ accum) {
  __shared__ float bacc;
  const int tid = threadIdx.x, l = tid & 63, w = tid >> 6;
  if (tid == 0) bacc = 0.f;
  __syncthreads();
  const int gw = blockIdx.x * 4 + w;
  const int NW = gridDim.x * 4;
  float lsum = 0.f;
  for (int p = gw; p < 65536; p += NW) {
    const float4 a = *(const float4*)&A[(size_t)p * CD + 4 * l];
    const float4 b = *(const float4*)&B[(size_t)p * CD + 4 * l];
    float ab = a.x * b.x + a.y * b.y + a.z * b.z + a.w * b.w;
    float aa = a.x * a.x + a.y * a.y + a.z * a.z + a.w * a.w;
    float bb = b.x * b.x + b.y * b.y + b.z * b.z + b.w * b.w;
    #pragma unroll
    for (int off = 32; off; off >>= 1) {
      ab += __shfl_xor(ab, off); aa += __shfl_xor(aa, off); bb += __shfl_xor(bb, off);
    }
    if (l == 0) lsum += ab / fmaxf(sqrtf(aa) * sqrtf(bb), 1e-8f);
  }
  if (l == 0) atomicAdd(&bacc, lsum);
  __syncthreads();
  if (tid == 0) atomicAdd(&accum[0], bacc);
}

__global__ void fin_kernel(const float* __restrict__ accum, float* __restrict__ out) {
  out[0] = -accum[0] / 65536.0f + accum[1];
}

extern "C" void kernel_launch(void* const* d_in, const int* in_sizes, int n_in,
                              void* d_out, int out_size, void* d_ws, size_t ws_size,
                              hipStream_t stream) {
  const float* logits  = (const float*)d_in[0];
  const float* logits1 = (const float*)d_in[1];
  const float* pfirst  = (const float*)d_in[2];
  const float* psec    = (const float*)d_in[3];
  float* out = (float*)d_out;
  float* wsf = (float*)d_ws;
  float* accum = wsf;                                  // [0]=sum of cos, [1]=sum of sse
  unsigned long long* cand = (unsigned long long*)(wsf + 16);  // 4*NS*8 u64 = 512 KB (8B-aligned)
  float* feaT = wsf + 16 + 4 * NS * NB_F * 2;          // after cand (131072 floats); 16B-aligned

  static std::once_flag once;
  std::call_once(once, []() {
    (void)hipFuncSetAttribute((const void*)branch_kernel,
                              hipFuncAttributeMaxDynamicSharedMemorySize, DYN_K);
    (void)hipGetLastError();
  });

  // zero accum + ALL cand slots (fresh slots each launch -> poll protocol is ABA-free)
  (void)hipMemsetAsync(wsf, 0, 64 + (size_t)4 * NS * NB_F * 8, stream);
  gp_kernel<<<1024, 256, 0, stream>>>(logits, logits1, accum);
  fps_kernel<<<4 * NB_F, TPB_F, 0, stream>>>(pfirst, psec, (int*)feaT, cand);
  branch_kernel<<<4, TPB, DYN_K, stream>>>(logits, logits1, pfirst, psec, feaT, accum);
  fin_kernel<<<1, 1, 0, stream>>>(accum, out);
}